// Round 4
// baseline (279.284 us; speedup 1.0000x reference)
//
#include <hip/hip_runtime.h>
#include <math.h>

// Problem constants
#define NCELLS 131072
#define IND 64
#define HD 128
#define OUTD 64
#define NF 8
#define FS 16384
#define DC 4096
#define TB 32             // cells per fused block (r4: 64->32, 4-wave barrier gang)
#define NBLK (NCELLS/TB)  // 4096
#define NTH 256
#define NREP 4            // atomic replication factor

typedef __bf16 bf16x8 __attribute__((ext_vector_type(8)));
typedef float f32x4 __attribute__((ext_vector_type(4)));
typedef unsigned short us8 __attribute__((ext_vector_type(8)));

#define MFMA(a,b,c) __builtin_amdgcn_mfma_f32_16x16x32_bf16(a,b,c,0,0,0)

// ---- workspace layout ----
// All weights stored FRAGMENT-SWIZZLED: for a [NCOLS][K] matrix, fragment
// (ctile,ktile) is a contiguous 512-us (1KB) chunk; within it, us index =
// lane*8 + e  holds  W[ctile*16 + (lane&15)][ktile*32 + (lane>>4)*8 + e].
// A wave loads a whole B-fragment with ONE coalesced global_load_dwordx4
// at  base + frag*512 + lane*8  (16B/lane, 1KB contiguous per wave).
#define WS_W1H 0          // [256][128]  h-part of fused [W1a;W1g]  (KT=4, 64 frags)
#define WS_W2F 32768      // [64][256]   fused [W2a | -W2g]         (KT=8, 32 frags)
#define WS_WIH 49152      // [384][64]   Wih out-cols only          (KT=2, 48 frags)
#define WS_WHH 73728      // [384][128]                             (KT=4, 96 frags)
#define WS_U_TOTAL 122880
// float region at (float*)((ushort*)ws + WS_U_TOTAL):
#define WF_B1   0         // [256] = b1 + x @ W1x.T   (fp32 exact fold)
#define WF_B2   256       // [64]
#define WF_WT   320       // [384] = Wih[:,64] fp32 (t-column)
#define WF_FSUM 704       // [NREP][8][128]
#define WF_WSUM 4800      // [NREP][64]
#define WF_SE   5056      // [NREP]
#define WF_TS   5060      // [NREP]
#define WF_TOTAL 5064
// aligned newh scratch (fp32) at byte offset: align256(122880*2 + 5064*4 = 266016)
#define WS_NH_OFF 266240

// ---- LDS layout (ushort units), total 13440 us = 26880 B -> 6 blocks/CU ----
#define L_SC    0         // [32][136] us : h bf16
#define L_SH1   4352      // [32][264] us : relu(h1) bf16
#define L_SOF_F 2176      // float idx (us 4352): [32][68] f32 out (overlays sh1)
#define L_SOB   8704      // [32][72] us : out bf16 (overlays sh1 tail)
#define L_ST_F  6400      // us 12800: [32] f32 t
#define L_SE_F  6432      // us 12864: [32] f32 e^t
#define L_WSCR_F 6464     // us 12928: [256] f32 reduction scratch
#define L_TOT   13440

__device__ __forceinline__ unsigned short f2bf(float f) {
    unsigned u = __builtin_bit_cast(unsigned, f);
    return (unsigned short)((u + 0x7FFFu + ((u >> 16) & 1u)) >> 16);
}
__device__ __forceinline__ float bf2f(unsigned short h) {
    return __builtin_bit_cast(float, (unsigned)h << 16);
}
__device__ __forceinline__ bf16x8 ld8(const unsigned short* p) {
    return __builtin_bit_cast(bf16x8, *(const us8*)p);
}
// fast activations: v_exp_f32 + v_rcp_f32
__device__ __forceinline__ float sigm(float v) {
    return __builtin_amdgcn_rcpf(1.f + __builtin_amdgcn_exp2f(-1.44269504f * v));
}
__device__ __forceinline__ float tanh_fast(float v) {
    return 1.f - 2.f * __builtin_amdgcn_rcpf(1.f + __builtin_amdgcn_exp2f(2.88539008f * v));
}

// ---- per-launch weight conversion fp32 -> bf16 fragment-swizzled ----
__global__ __launch_bounds__(256) void convert_kernel(
    const float* __restrict__ x,
    const float* __restrict__ W1a, const float* __restrict__ b1a,
    const float* __restrict__ W2a, const float* __restrict__ b2a,
    const float* __restrict__ W1g, const float* __restrict__ b1g,
    const float* __restrict__ W2g, const float* __restrict__ b2g,
    const float* __restrict__ Wih, const float* __restrict__ Whh,
    unsigned short* __restrict__ wsu, float* __restrict__ wsf)
{
    int i = blockIdx.x * 256 + threadIdx.x;
    if (i < 32768) {                         // W1H, KT=4
        int frag = i >> 9, r = i & 511;
        int lane = r >> 3, e = r & 7;
        int col = (frag >> 2)*16 + (lane & 15);
        int k   = (frag & 3)*32 + (lane >> 4)*8 + e;
        float v = (col < 128) ? W1a[col*192 + 64 + k] : W1g[(col-128)*192 + 64 + k];
        wsu[WS_W1H + i] = f2bf(v); return;
    }
    int j = i - 32768;
    if (j < 16384) {                         // W2F, KT=8
        int frag = j >> 9, r = j & 511;
        int lane = r >> 3, e = r & 7;
        int col = (frag >> 3)*16 + (lane & 15);
        int k   = (frag & 7)*32 + (lane >> 4)*8 + e;
        float v = (k < 128) ? W2a[col*128 + k] : -W2g[col*128 + (k-128)];
        wsu[WS_W2F + j] = f2bf(v); return;
    }
    j -= 16384;
    if (j < 24576) {                         // WIH (out-cols), KT=2
        int frag = j >> 9, r = j & 511;
        int lane = r >> 3, e = r & 7;
        int col = (frag >> 1)*16 + (lane & 15);
        int k   = (frag & 1)*32 + (lane >> 4)*8 + e;
        wsu[WS_WIH + j] = f2bf(Wih[col*65 + k]); return;
    }
    j -= 24576;
    if (j < 49152) {                         // WHH, KT=4
        int frag = j >> 9, r = j & 511;
        int lane = r >> 3, e = r & 7;
        int col = (frag >> 2)*16 + (lane & 15);
        int k   = (frag & 3)*32 + (lane >> 4)*8 + e;
        wsu[WS_WHH + j] = f2bf(Whh[col*128 + k]); return;
    }
    j -= 49152;
    if (j < 256) {                           // b1' = b1 + x @ W1x.T  (fp32)
        const float* wr = (j < 128) ? (W1a + j*192) : (W1g + (size_t)(j-128)*192);
        float base = (j < 128) ? b1a[j] : b1g[j-128];
        float dot = 0.f;
        #pragma unroll 8
        for (int k = 0; k < 64; ++k) dot += x[k] * wr[k];
        wsf[WF_B1 + j] = base + dot; return;
    }
    j -= 256;
    if (j < 64)  { wsf[WF_B2 + j] = b2a[j] - b2g[j]; return; }
    j -= 64;
    if (j < 384) { wsf[WF_WT + j] = Wih[j*65 + 64]; return; }
}

// ---- fused per-cell pipeline, bf16 MFMA, TB=32, 4 waves ----
// NOTE: __launch_bounds__ 2nd arg relaxed (4). Tighter values provoked a
// 40-VGPR allocation with scratch spills (r2: WRITE_SIZE 67->424 MB).
__global__ __launch_bounds__(NTH, 4) void fused_cell_kernel(
    const float* __restrict__ hiddens,
    const float* __restrict__ bih, const float* __restrict__ bhh,
    const unsigned short* __restrict__ wsu, const float* __restrict__ wsf,
    float* __restrict__ newh, float* __restrict__ fsum,
    float* __restrict__ wsum, float* __restrict__ sumexp, float* __restrict__ tsum)
{
    __shared__ __align__(16) unsigned short sm[L_TOT];
    float* smf = (float*)sm;

    const int tid = threadIdx.x;
    const int cell0 = blockIdx.x * TB;
    const int w = tid >> 6, lane = tid & 63;
    const int q = lane >> 4, cL = lane & 15;
    const int rep = blockIdx.x & (NREP-1);

    // ---- phase 0: stage h bf16 into sc [32][136] ----
    for (int idx = tid; idx < TB*(HD/4); idx += NTH) {
        int c = idx >> 5, k4 = idx & 31;
        float4 v = ((const float4*)hiddens)[(size_t)(cell0+c)*(HD/4) + k4];
        unsigned p0 = (unsigned)f2bf(v.x) | ((unsigned)f2bf(v.y) << 16);
        unsigned p1 = (unsigned)f2bf(v.z) | ((unsigned)f2bf(v.w) << 16);
        *(unsigned*)&sm[L_SC + c*136 + k4*4]     = p0;
        *(unsigned*)&sm[L_SC + c*136 + k4*4 + 2] = p1;
    }
    __syncthreads();

    // ---- phase 1: GEMM1  h1 = relu(h @ W1h.T + b1'), K=128, cols 256 ----
    // wave w: cols w*64 .. w*64+63 (4 col-tiles), both M-tiles (rows 0..31)
    #pragma unroll
    for (int ct = 0; ct < 4; ++ct) {
        const int col = w*64 + ct*16 + cL;
        const float bias = wsf[WF_B1 + col];
        f32x4 acc[2];
        #pragma unroll
        for (int m = 0; m < 2; ++m) acc[m] = (f32x4){bias,bias,bias,bias};
        const unsigned short* wp = wsu + WS_W1H + (w*4 + ct)*4*512 + lane*8;
        #pragma unroll
        for (int k = 0; k < 4; ++k) {
            bf16x8 B = ld8(wp + k*512);
            #pragma unroll
            for (int m = 0; m < 2; ++m) {
                bf16x8 A = ld8(&sm[L_SC + (m*16+cL)*136 + k*32 + q*8]);
                acc[m] = MFMA(A, B, acc[m]);
            }
        }
        #pragma unroll
        for (int m = 0; m < 2; ++m)
            #pragma unroll
            for (int r = 0; r < 4; ++r)
                sm[L_SH1 + (m*16+q*4+r)*264 + col] = f2bf(fmaxf(acc[m][r], 0.f));
    }
    __syncthreads();

    // ---- phase 2: GEMM2  out = h1 @ W2f.T + b2f ----
    // wave w: col-tile w, both M-tiles
    f32x4 o0, o1;
    {
        const int col = w*16 + cL;
        const float bias = wsf[WF_B2 + col];
        o0 = (f32x4){bias,bias,bias,bias}; o1 = o0;
        const unsigned short* wp = wsu + WS_W2F + w*8*512 + lane*8;
        #pragma unroll
        for (int k = 0; k < 8; ++k) {
            bf16x8 B  = ld8(wp + k*512);
            bf16x8 A0 = ld8(&sm[L_SH1 + (cL)*264 + k*32 + q*8]);
            o0 = MFMA(A0, B, o0);
            bf16x8 A1 = ld8(&sm[L_SH1 + (16+cL)*264 + k*32 + q*8]);
            o1 = MFMA(A1, B, o1);
        }
    }
    __syncthreads();   // all sh1 reads done; overlay region now writable

    // ---- phase 2b: out tiles into overlay (sof fp32, sob bf16) ----
    {
        const int col = w*16 + cL;
        #pragma unroll
        for (int r = 0; r < 4; ++r) {
            int r0 = q*4 + r, r1 = 16 + q*4 + r;
            smf[L_SOF_F + r0*68 + col] = o0[r];
            sm [L_SOB   + r0*72 + col] = f2bf(o0[r]);
            smf[L_SOF_F + r1*68 + col] = o1[r];
            sm [L_SOB   + r1*72 + col] = f2bf(o1[r]);
        }
    }
    __syncthreads();

    // ---- phase 3: t = mean(out^2), e^t  (all 256 threads; 8 lanes per cell) ----
    {
        const int c = tid >> 3, g = tid & 7;
        f32x4 a = *(const f32x4*)&smf[L_SOF_F + c*68 + g*8];
        f32x4 b = *(const f32x4*)&smf[L_SOF_F + c*68 + g*8 + 4];
        float s = a[0]*a[0] + a[1]*a[1] + a[2]*a[2] + a[3]*a[3]
                + b[0]*b[0] + b[1]*b[1] + b[2]*b[2] + b[3]*b[3];
        s += __shfl_xor(s, 1);
        s += __shfl_xor(s, 2);
        s += __shfl_xor(s, 4);
        if (g == 0) {
            float t = s * (1.0f/OUTD);
            smf[L_ST_F + c] = t;
            smf[L_SE_F + c] = __builtin_amdgcn_exp2f(t * 1.44269504f);
        }
    }
    __syncthreads();

    // ---- phase 4: GRU gates (fragment-swizzled B loads; t as fp32 rank-1 fix) ----
    // wave w covers j-tiles {w, 4+w}, both M-tiles each
    const int fidx = (int)(blockIdx.x >> 9);     // 512 blocks per faction
    {
        float colsum;
        #pragma unroll
        for (int jt2 = 0; jt2 < 2; ++jt2) {
            const int jt = jt2*4 + w;
            const int j  = jt*16 + cL;           // hidden unit for this lane
            const float bR = bih[j]      + bhh[j];
            const float bZ = bih[HD+j]   + bhh[HD+j];
            const float bI = bih[2*HD+j];
            const float bH = bhh[2*HD+j];
            const float wtR = wsf[WF_WT + j];
            const float wtZ = wsf[WF_WT + HD + j];
            const float wtI = wsf[WF_WT + 2*HD + j];
            const unsigned short* wiB = wsu + WS_WIH + lane*8;
            const unsigned short* whB = wsu + WS_WHH + lane*8;
            f32x4 R0 = {bR,bR,bR,bR}, R1 = R0;
            f32x4 Z0 = {bZ,bZ,bZ,bZ}, Z1 = Z0;
            f32x4 I0 = {bI,bI,bI,bI}, I1 = I0;
            f32x4 H0 = {bH,bH,bH,bH}, H1 = H0;
            #pragma unroll
            for (int k = 0; k < 2; ++k) {        // gi: K=64, KT=2
                bf16x8 Br = ld8(wiB + ((     jt)*2 + k)*512);
                bf16x8 Bz = ld8(wiB + (( 8 + jt)*2 + k)*512);
                bf16x8 Bi = ld8(wiB + ((16 + jt)*2 + k)*512);
                bf16x8 A0 = ld8(&sm[L_SOB + (cL)*72 + k*32 + q*8]);
                bf16x8 A1 = ld8(&sm[L_SOB + (16+cL)*72 + k*32 + q*8]);
                R0 = MFMA(A0, Br, R0); R1 = MFMA(A1, Br, R1);
                Z0 = MFMA(A0, Bz, Z0); Z1 = MFMA(A1, Bz, Z1);
                I0 = MFMA(A0, Bi, I0); I1 = MFMA(A1, Bi, I1);
            }
            #pragma unroll
            for (int k = 0; k < 4; ++k) {        // gh: K=128, KT=4
                bf16x8 Br = ld8(whB + ((     jt)*4 + k)*512);
                bf16x8 Bz = ld8(whB + (( 8 + jt)*4 + k)*512);
                bf16x8 Bn = ld8(whB + ((16 + jt)*4 + k)*512);
                bf16x8 A0 = ld8(&sm[L_SC + (cL)*136 + k*32 + q*8]);
                bf16x8 A1 = ld8(&sm[L_SC + (16+cL)*136 + k*32 + q*8]);
                R0 = MFMA(A0, Br, R0); R1 = MFMA(A1, Br, R1);
                Z0 = MFMA(A0, Bz, Z0); Z1 = MFMA(A1, Bz, Z1);
                H0 = MFMA(A0, Bn, H0); H1 = MFMA(A1, Bn, H1);
            }
            colsum = 0.f;
            #pragma unroll
            for (int r = 0; r < 4; ++r) {
                const int row = q*4 + r;
                const float tv = smf[L_ST_F + row];
                const float rr = sigm(R0[r] + tv*wtR);
                const float zz = sigm(Z0[r] + tv*wtZ);
                const float nn = tanh_fast(I0[r] + tv*wtI + rr*H0[r]);
                const float hold = bf2f(sm[L_SC + row*136 + j]);
                const float hv = (1.f - zz)*nn + zz*hold;
                newh[(size_t)(cell0+row)*HD + j] = hv;
                colsum += hv;
            }
            #pragma unroll
            for (int r = 0; r < 4; ++r) {
                const int row = 16 + q*4 + r;
                const float tv = smf[L_ST_F + row];
                const float rr = sigm(R1[r] + tv*wtR);
                const float zz = sigm(Z1[r] + tv*wtZ);
                const float nn = tanh_fast(I1[r] + tv*wtI + rr*H1[r]);
                const float hold = bf2f(sm[L_SC + row*136 + j]);
                const float hv = (1.f - zz)*nn + zz*hold;
                newh[(size_t)(cell0+row)*HD + j] = hv;
                colsum += hv;
            }
            colsum += __shfl_xor(colsum, 16);
            colsum += __shfl_xor(colsum, 32);
            if (q == 0) unsafeAtomicAdd(&fsum[(rep*NF + fidx)*HD + j], colsum);
        }
    }

    // ---- phase 5: softmax-weighted sums, parallel across all 4 waves ----
    {
        const int col = tid & 63, cg = tid >> 6;
        float wacc = 0.f;
        #pragma unroll
        for (int c8 = 0; c8 < 8; ++c8) {
            const int c = cg*8 + c8;
            wacc += smf[L_SE_F + c] * smf[L_SOF_F + c*68 + col];
        }
        smf[L_WSCR_F + cg*64 + col] = wacc;
    }
    __syncthreads();
    if (tid < 64) {
        float wacc = 0.f;
        #pragma unroll
        for (int g = 0; g < 4; ++g) wacc += smf[L_WSCR_F + g*64 + tid];
        unsafeAtomicAdd(&wsum[rep*64 + tid], wacc);
    }
    if (tid < 32) {
        float e = smf[L_SE_F + tid];
        float t = smf[L_ST_F + tid];
        #pragma unroll
        for (int d = 1; d < 32; d <<= 1) { e += __shfl_xor(e, d); t += __shfl_xor(t, d); }
        if (tid == 0) { unsafeAtomicAdd(&sumexp[rep], e); unsafeAtomicAdd(&tsum[rep], t); }
    }
}

// ---- faction sync: dst = a*src + b[j]; block 0 also computes the pred head ----
#define TBF 64
__global__ __launch_bounds__(256) void faction_kernel(
    const float* __restrict__ src, float* __restrict__ dst,
    const float* __restrict__ fsum, const int* __restrict__ step,
    const float* __restrict__ Wo, const float* __restrict__ bo,
    const float* __restrict__ wsum, const float* __restrict__ sumexp,
    const float* __restrict__ tsum, float* __restrict__ d_out)
{
    __shared__ float bnon[HD], bdeb[HD];
    const int cell0 = blockIdx.x * TBF;
    const int f = blockIdx.x >> 8;            // 256 blocks per faction
    if (threadIdx.x < HD) {
        const int jc = threadIdx.x;
        float s = 0.f, fm_s = 0.f;
        #pragma unroll
        for (int rr = 0; rr < NREP; ++rr) {
            #pragma unroll
            for (int ff = 0; ff < NF; ++ff) s += fsum[(rr*NF+ff)*HD + jc];
            fm_s += fsum[(rr*NF+f)*HD + jc];
        }
        const float go = s * (1.0f/NCELLS);
        const float fm = fm_s * (1.0f/FS);
        bnon[jc] = 0.15f*fm;
        bdeb[jc] = 0.1275f*fm + 0.15f*go;
    }
    __syncthreads();
    const bool debate = (step[0] > 5) && ((cell0 & (FS-1)) < DC);  // uniform per block
    const float a = debate ? 0.7225f : 0.85f;
    const float* brow = debate ? bdeb : bnon;
    const float* srow = src + (size_t)cell0*HD;
    float* drow = dst + (size_t)cell0*HD;
    if ((((uintptr_t)srow) & 15) == 0) {
        const float4* s4 = (const float4*)srow;
        #pragma unroll
        for (int i = 0; i < (TBF*HD)/(256*4); ++i) {
            const int idx4 = threadIdx.x + i*256;
            const int jb = (idx4 & 31)*4;
            float4 v = s4[idx4];
            float r0 = a*v.x + brow[jb];
            float r1 = a*v.y + brow[jb+1];
            float r2 = a*v.z + brow[jb+2];
            float r3 = a*v.w + brow[jb+3];
            float* dp = drow + (size_t)idx4*4;   // dst may be only 4B-aligned
            dp[0] = r0; dp[1] = r1; dp[2] = r2; dp[3] = r3;
        }
    } else {
        #pragma unroll
        for (int i = 0; i < (TBF*HD)/256; ++i) {
            const int idx = threadIdx.x + i*256;
            const int jb = idx & 127;
            drow[idx] = a*srow[idx] + brow[jb];
        }
    }
    if (blockIdx.x == 0 && threadIdx.x < OUTD) {  // fused final head
        const int i = threadIdx.x;
        float seT = 0.f;
        #pragma unroll
        for (int rr = 0; rr < NREP; ++rr) seT += sumexp[rr];
        const float inv = 1.0f / seT;
        const float* wr = Wo + (size_t)i*OUTD;
        float acc = bo[i];
        #pragma unroll 8
        for (int jj = 0; jj < OUTD; ++jj) {
            float wv = wsum[jj] + wsum[64+jj] + wsum[128+jj] + wsum[192+jj];
            acc += (wv*inv) * wr[jj];
        }
        d_out[i] = acc;
        if (i == 0) {
            float tT = 0.f;
            #pragma unroll
            for (int rr = 0; rr < NREP; ++rr) tT += tsum[rr];
            d_out[OUTD] = tT * (1.0f/NCELLS);
        }
    }
}

extern "C" void kernel_launch(void* const* d_in, const int* in_sizes, int n_in,
                              void* d_out, int out_size, void* d_ws, size_t ws_size,
                              hipStream_t stream)
{
    const float* x   = (const float*)d_in[0];
    const float* hid = (const float*)d_in[1];
    const float* W1a = (const float*)d_in[2];
    const float* b1a = (const float*)d_in[3];
    const float* W2a = (const float*)d_in[4];
    const float* b2a = (const float*)d_in[5];
    const float* W1g = (const float*)d_in[6];
    const float* b1g = (const float*)d_in[7];
    const float* W2g = (const float*)d_in[8];
    const float* b2g = (const float*)d_in[9];
    const float* Wih = (const float*)d_in[10];
    const float* Whh = (const float*)d_in[11];
    const float* bih = (const float*)d_in[12];
    const float* bhh = (const float*)d_in[13];
    const float* Wo  = (const float*)d_in[14];
    const float* bo  = (const float*)d_in[15];
    const int*  step = (const int*)d_in[16];

    float* out  = (float*)d_out;
    float* newh_out = out + (OUTD + 1);

    unsigned short* wsu = (unsigned short*)d_ws;
    float* wsf = (float*)(wsu + WS_U_TOTAL);
    float* fsum   = wsf + WF_FSUM;
    float* wsum   = wsf + WF_WSUM;
    float* sumexp = wsf + WF_SE;
    float* tsum   = wsf + WF_TS;

    // aligned pre-sync newh scratch if workspace allows; else in-place in d_out
    const size_t need = (size_t)WS_NH_OFF + (size_t)NCELLS*HD*sizeof(float);
    float* nh_store = (ws_size >= need) ? (float*)((char*)d_ws + WS_NH_OFF) : newh_out;

    hipMemsetAsync(fsum, 0, (NREP*NF*HD + NREP*OUTD + 2*NREP)*sizeof(float), stream);

    // total convert elements: 32768+16384+24576+49152+256+64+384 = 123584
    convert_kernel<<<(123584 + 255)/256, 256, 0, stream>>>(
        x, W1a, b1a, W2a, b2a, W1g, b1g, W2g, b2g, Wih, Whh, wsu, wsf);

    fused_cell_kernel<<<NBLK, NTH, 0, stream>>>(
        hid, bih, bhh, wsu, wsf, nh_store, fsum, wsum, sumexp, tsum);

    faction_kernel<<<NCELLS/TBF, 256, 0, stream>>>(
        nh_store, newh_out, fsum, step, Wo, bo, wsum, sumexp, tsum, out);
}

// Round 5
// 231.019 us; speedup vs baseline: 1.2089x; 1.2089x over previous
//
#include <hip/hip_runtime.h>
#include <math.h>

// Problem constants
#define NCELLS 131072
#define IND 64
#define HD 128
#define OUTD 64
#define NF 8
#define FS 16384
#define DC 4096
#define TB 64             // cells per fused block (r5: back to r3's 64; r4's 32 was -37%)
#define NBLK (NCELLS/TB)  // 2048
#define NTH 512
#define NREP 4            // atomic replication factor
#define NT (NCELLS*HD)    // 16777216 total newh elements

typedef __bf16 bf16x8 __attribute__((ext_vector_type(8)));
typedef float f32x4 __attribute__((ext_vector_type(4)));
typedef unsigned short us8 __attribute__((ext_vector_type(8)));

#define MFMA(a,b,c) __builtin_amdgcn_mfma_f32_16x16x32_bf16(a,b,c,0,0,0)

// ---- workspace layout ----
// All weights stored FRAGMENT-SWIZZLED (see r2): fragment = contiguous 1KB,
// one coalesced global_load_dwordx4 per wave at base + frag*512 + lane*8.
#define WS_W1H 0          // [256][128]  (KT=4, 64 frags)
#define WS_W2F 32768      // [64][256]   (KT=8, 32 frags)
#define WS_WIH 49152      // [384][64]   (KT=2, 48 frags)
#define WS_WHH 73728      // [384][128]  (KT=4, 96 frags)
#define WS_U_TOTAL 122880
// float region at (float*)((ushort*)ws + WS_U_TOTAL):
#define WF_B1   0         // [256] = b1 + x @ W1x.T
#define WF_B2   256       // [64]
#define WF_WT   320       // [384] = Wih[:,64] fp32
#define WF_FSUM 704       // [NREP][8][128]
#define WF_WSUM 4800      // [NREP][64]
#define WF_SE   5056
#define WF_TS   5060
#define WF_TOTAL 5064
#define WS_NH_OFF 266240  // align256; newh scratch (fp32, shifted layout)

// ---- LDS layout (ushort units), total 25600 us = 51200 B ----
#define L_SC    0         // [64][136] us : h bf16
#define L_SH1   8704      // [64][264] us : relu(h1) bf16
#define L_SOF_F 4352      // float idx (us 8704): [64][68] f32 out (overlays sh1)
#define L_SOB   17408     // [64][72] us : out bf16
#define L_ST_F  11008     // [64] f32 t
#define L_SE_F  11072     // [64] f32 e^t
#define L_WSCR_F 11136    // [512] f32 reduction scratch
#define L_TOT   25600

__device__ __forceinline__ unsigned short f2bf(float f) {
    unsigned u = __builtin_bit_cast(unsigned, f);
    return (unsigned short)((u + 0x7FFFu + ((u >> 16) & 1u)) >> 16);
}
__device__ __forceinline__ float bf2f(unsigned short h) {
    return __builtin_bit_cast(float, (unsigned)h << 16);
}
__device__ __forceinline__ bf16x8 ld8(const unsigned short* p) {
    return __builtin_bit_cast(bf16x8, *(const us8*)p);
}
__device__ __forceinline__ float sigm(float v) {
    return __builtin_amdgcn_rcpf(1.f + __builtin_amdgcn_exp2f(-1.44269504f * v));
}
__device__ __forceinline__ float tanh_fast(float v) {
    return 1.f - 2.f * __builtin_amdgcn_rcpf(1.f + __builtin_amdgcn_exp2f(2.88539008f * v));
}

// ---- per-launch weight conversion fp32 -> bf16 fragment-swizzled ----
__global__ __launch_bounds__(256) void convert_kernel(
    const float* __restrict__ x,
    const float* __restrict__ W1a, const float* __restrict__ b1a,
    const float* __restrict__ W2a, const float* __restrict__ b2a,
    const float* __restrict__ W1g, const float* __restrict__ b1g,
    const float* __restrict__ W2g, const float* __restrict__ b2g,
    const float* __restrict__ Wih, const float* __restrict__ Whh,
    unsigned short* __restrict__ wsu, float* __restrict__ wsf)
{
    int i = blockIdx.x * 256 + threadIdx.x;
    if (i < 32768) {                         // W1H, KT=4
        int frag = i >> 9, r = i & 511;
        int lane = r >> 3, e = r & 7;
        int col = (frag >> 2)*16 + (lane & 15);
        int k   = (frag & 3)*32 + (lane >> 4)*8 + e;
        float v = (col < 128) ? W1a[col*192 + 64 + k] : W1g[(col-128)*192 + 64 + k];
        wsu[WS_W1H + i] = f2bf(v); return;
    }
    int j = i - 32768;
    if (j < 16384) {                         // W2F, KT=8
        int frag = j >> 9, r = j & 511;
        int lane = r >> 3, e = r & 7;
        int col = (frag >> 3)*16 + (lane & 15);
        int k   = (frag & 7)*32 + (lane >> 4)*8 + e;
        float v = (k < 128) ? W2a[col*128 + k] : -W2g[col*128 + (k-128)];
        wsu[WS_W2F + j] = f2bf(v); return;
    }
    j -= 16384;
    if (j < 24576) {                         // WIH (out-cols), KT=2
        int frag = j >> 9, r = j & 511;
        int lane = r >> 3, e = r & 7;
        int col = (frag >> 1)*16 + (lane & 15);
        int k   = (frag & 1)*32 + (lane >> 4)*8 + e;
        wsu[WS_WIH + j] = f2bf(Wih[col*65 + k]); return;
    }
    j -= 24576;
    if (j < 49152) {                         // WHH, KT=4
        int frag = j >> 9, r = j & 511;
        int lane = r >> 3, e = r & 7;
        int col = (frag >> 2)*16 + (lane & 15);
        int k   = (frag & 3)*32 + (lane >> 4)*8 + e;
        wsu[WS_WHH + j] = f2bf(Whh[col*128 + k]); return;
    }
    j -= 49152;
    if (j < 256) {                           // b1' = b1 + x @ W1x.T  (fp32)
        const float* wr = (j < 128) ? (W1a + j*192) : (W1g + (size_t)(j-128)*192);
        float base = (j < 128) ? b1a[j] : b1g[j-128];
        float dot = 0.f;
        #pragma unroll 8
        for (int k = 0; k < 64; ++k) dot += x[k] * wr[k];
        wsf[WF_B1 + j] = base + dot; return;
    }
    j -= 256;
    if (j < 64)  { wsf[WF_B2 + j] = b2a[j] - b2g[j]; return; }
    j -= 64;
    if (j < 384) { wsf[WF_WT + j] = Wih[j*65 + 64]; return; }
}

// ---- fused per-cell pipeline, TB=64, 8 waves, software-pipelined B prefetch ----
// launch_bounds (512,4): VGPR cap 128. Tighter caps spill (r2: WRITE 67->424MB).
__global__ __launch_bounds__(NTH, 4) void fused_cell_kernel(
    const float* __restrict__ hiddens,
    const float* __restrict__ bih, const float* __restrict__ bhh,
    const unsigned short* __restrict__ wsu, const float* __restrict__ wsf,
    float* __restrict__ newh, float* __restrict__ fsum,
    float* __restrict__ wsum, float* __restrict__ sumexp, float* __restrict__ tsum,
    int shifted)
{
    __shared__ __align__(16) unsigned short sm[L_TOT];
    float* smf = (float*)sm;

    const int tid = threadIdx.x;
    const int cell0 = blockIdx.x * TB;
    const int w = tid >> 6, lane = tid & 63;
    const int q = lane >> 4, cL = lane & 15;
    const int rep = blockIdx.x & (NREP-1);

    // ---- prefetch GEMM1 B frags (8): issued before phase-0 staging loads,
    //      complete during staging; barrier drain finds them done ----
    bf16x8 pB1[8];
    {
        const unsigned short* wp = wsu + WS_W1H + (w*2)*4*512 + lane*8;
        #pragma unroll
        for (int k = 0; k < 8; ++k) pB1[k] = ld8(wp + k*512);
    }

    // ---- phase 0: stage h bf16 into sc [64][136] ----
    for (int idx = tid; idx < TB*(HD/4); idx += NTH) {
        int c = idx >> 5, k4 = idx & 31;
        float4 v = ((const float4*)hiddens)[(size_t)(cell0+c)*(HD/4) + k4];
        unsigned p0 = (unsigned)f2bf(v.x) | ((unsigned)f2bf(v.y) << 16);
        unsigned p1 = (unsigned)f2bf(v.z) | ((unsigned)f2bf(v.w) << 16);
        *(unsigned*)&sm[L_SC + c*136 + k4*4]     = p0;
        *(unsigned*)&sm[L_SC + c*136 + k4*4 + 2] = p1;
    }
    __syncthreads();

    // ---- phase 1: GEMM1 (prefetch GEMM2 B at top, hidden under MFMAs) ----
    bf16x8 pB2[8];
    {
        const unsigned short* wp = wsu + WS_W2F + (w & 3)*8*512 + lane*8;
        #pragma unroll
        for (int k = 0; k < 8; ++k) pB2[k] = ld8(wp + k*512);
    }
    #pragma unroll
    for (int ct = 0; ct < 2; ++ct) {
        const int col = w*32 + ct*16 + cL;
        const float bias = wsf[WF_B1 + col];
        f32x4 acc[4];
        #pragma unroll
        for (int m = 0; m < 4; ++m) acc[m] = (f32x4){bias,bias,bias,bias};
        #pragma unroll
        for (int k = 0; k < 4; ++k) {
            bf16x8 B = pB1[ct*4 + k];
            #pragma unroll
            for (int m = 0; m < 4; ++m) {
                bf16x8 A = ld8(&sm[L_SC + (m*16+cL)*136 + k*32 + q*8]);
                acc[m] = MFMA(A, B, acc[m]);
            }
        }
        #pragma unroll
        for (int m = 0; m < 4; ++m)
            #pragma unroll
            for (int r = 0; r < 4; ++r)
                sm[L_SH1 + (m*16+q*4+r)*264 + col] = f2bf(fmaxf(acc[m][r], 0.f));
    }
    __syncthreads();

    // ---- phase 2: GEMM2 (prefetch GRU gi B at top, hidden under MFMAs) ----
    bf16x8 pGi[6];
    {
        const unsigned short* wiB = wsu + WS_WIH + lane*8;
        #pragma unroll
        for (int k = 0; k < 2; ++k) {
            pGi[k]   = ld8(wiB + ((     w)*2 + k)*512);
            pGi[2+k] = ld8(wiB + (( 8 + w)*2 + k)*512);
            pGi[4+k] = ld8(wiB + ((16 + w)*2 + k)*512);
        }
    }
    f32x4 o0, o1;
    {
        const int Mt0 = (w >> 2)*2, Mt1 = Mt0 + 1;
        const float bias = wsf[WF_B2 + (w & 3)*16 + cL];
        o0 = (f32x4){bias,bias,bias,bias}; o1 = o0;
        #pragma unroll
        for (int k = 0; k < 8; ++k) {
            bf16x8 B  = pB2[k];
            bf16x8 A0 = ld8(&sm[L_SH1 + (Mt0*16+cL)*264 + k*32 + q*8]);
            o0 = MFMA(A0, B, o0);
            bf16x8 A1 = ld8(&sm[L_SH1 + (Mt1*16+cL)*264 + k*32 + q*8]);
            o1 = MFMA(A1, B, o1);
        }
    }
    __syncthreads();   // all sh1 reads done; overlay region now writable

    // ---- phase 2b: out tiles into overlay (sof fp32, sob bf16) ----
    {
        const int col = (w & 3)*16 + cL;
        const int Mt0 = (w >> 2)*2, Mt1 = Mt0 + 1;
        #pragma unroll
        for (int r = 0; r < 4; ++r) {
            int r0 = Mt0*16 + q*4 + r, r1 = Mt1*16 + q*4 + r;
            smf[L_SOF_F + r0*68 + col] = o0[r];
            sm [L_SOB   + r0*72 + col] = f2bf(o0[r]);
            smf[L_SOF_F + r1*68 + col] = o1[r];
            sm [L_SOB   + r1*72 + col] = f2bf(o1[r]);
        }
    }
    __syncthreads();

    // ---- phase 3: t = mean(out^2), e^t ----
    {
        const int c = tid >> 3, g = tid & 7;
        f32x4 a = *(const f32x4*)&smf[L_SOF_F + c*68 + g*8];
        f32x4 b = *(const f32x4*)&smf[L_SOF_F + c*68 + g*8 + 4];
        float s = a[0]*a[0] + a[1]*a[1] + a[2]*a[2] + a[3]*a[3]
                + b[0]*b[0] + b[1]*b[1] + b[2]*b[2] + b[3]*b[3];
        s += __shfl_xor(s, 1);
        s += __shfl_xor(s, 2);
        s += __shfl_xor(s, 4);
        if (g == 0) {
            float t = s * (1.0f/OUTD);
            smf[L_ST_F + c] = t;
            smf[L_SE_F + c] = __builtin_amdgcn_exp2f(t * 1.44269504f);
        }
    }
    __syncthreads();

    // ---- phase 4: GRU gates, merged 4-M-tile pass (gh B loads deduped 24->12) ----
    const int fidx = (int)(blockIdx.x >> 8);
    {
        const int j = w*16 + cL;
        const float bR = bih[j]      + bhh[j];
        const float bZ = bih[HD+j]   + bhh[HD+j];
        const float bI = bih[2*HD+j];
        const float bH = bhh[2*HD+j];
        const float wtR = wsf[WF_WT + j];
        const float wtZ = wsf[WF_WT + HD + j];
        const float wtI = wsf[WF_WT + 2*HD + j];
        f32x4 R[4], Z[4], I[4], H[4];
        #pragma unroll
        for (int m = 0; m < 4; ++m) {
            R[m] = (f32x4){bR,bR,bR,bR}; Z[m] = (f32x4){bZ,bZ,bZ,bZ};
            I[m] = (f32x4){bI,bI,bI,bI}; H[m] = (f32x4){bH,bH,bH,bH};
        }
        #pragma unroll
        for (int k = 0; k < 2; ++k) {        // gi: K=64
            bf16x8 Br = pGi[k], Bz = pGi[2+k], Bi = pGi[4+k];
            #pragma unroll
            for (int m = 0; m < 4; ++m) {
                bf16x8 A = ld8(&sm[L_SOB + (m*16+cL)*72 + k*32 + q*8]);
                R[m] = MFMA(A, Br, R[m]);
                Z[m] = MFMA(A, Bz, Z[m]);
                I[m] = MFMA(A, Bi, I[m]);
            }
        }
        const unsigned short* whB = wsu + WS_WHH + lane*8;
        #pragma unroll
        for (int k = 0; k < 4; ++k) {        // gh: K=128
            bf16x8 Br = ld8(whB + ((     w)*4 + k)*512);
            bf16x8 Bz = ld8(whB + (( 8 + w)*4 + k)*512);
            bf16x8 Bn = ld8(whB + ((16 + w)*4 + k)*512);
            #pragma unroll
            for (int m = 0; m < 4; ++m) {
                bf16x8 A = ld8(&sm[L_SC + (m*16+cL)*136 + k*32 + q*8]);
                R[m] = MFMA(A, Br, R[m]);
                Z[m] = MFMA(A, Bz, Z[m]);
                H[m] = MFMA(A, Bn, H[m]);
            }
        }
        float colsum = 0.f;
        #pragma unroll
        for (int m = 0; m < 4; ++m) {
            #pragma unroll
            for (int r = 0; r < 4; ++r) {
                const int row = m*16 + q*4 + r;
                const float tv = smf[L_ST_F + row];
                const float rr = sigm(R[m][r] + tv*wtR);
                const float zz = sigm(Z[m][r] + tv*wtZ);
                const float nn = tanh_fast(I[m][r] + tv*wtI + rr*H[m][r]);
                const float hold = bf2f(sm[L_SC + row*136 + j]);
                const float hv = (1.f - zz)*nn + zz*hold;
                int g = (cell0+row)*HD + j;
                int s = g - 3;
                if (g < 3) s = NT - 3 + g;   // wrap head into free tail slots
                if (!shifted) s = g;
                newh[s] = hv;
                colsum += hv;
            }
        }
        colsum += __shfl_xor(colsum, 16);
        colsum += __shfl_xor(colsum, 32);
        if (q == 0) unsafeAtomicAdd(&fsum[(rep*NF + fidx)*HD + j], colsum);
    }

    // ---- phase 5: softmax-weighted sums ----
    {
        const int col = tid & 63, cg = tid >> 6;
        float wacc = 0.f;
        #pragma unroll
        for (int c8 = 0; c8 < 8; ++c8) {
            const int c = cg*8 + c8;
            wacc += smf[L_SE_F + c] * smf[L_SOF_F + c*68 + col];
        }
        smf[L_WSCR_F + cg*64 + col] = wacc;
    }
    __syncthreads();
    if (tid < 64) {
        float wacc = 0.f;
        #pragma unroll
        for (int g = 0; g < 8; ++g) wacc += smf[L_WSCR_F + g*64 + tid];
        unsafeAtomicAdd(&wsum[rep*64 + tid], wacc);
        float e = smf[L_SE_F + tid];
        float t = smf[L_ST_F + tid];
        #pragma unroll
        for (int d = 1; d < 64; d <<= 1) { e += __shfl_xor(e, d); t += __shfl_xor(t, d); }
        if (tid == 0) { unsafeAtomicAdd(&sumexp[rep], e); unsafeAtomicAdd(&tsum[rep], t); }
    }
}

// ---- faction sync; shifted path: aligned f4 loads AND aligned f4 stores ----
#define TBF 64
__global__ __launch_bounds__(256) void faction_kernel(
    const float* __restrict__ src, float* __restrict__ dst,
    const float* __restrict__ fsum, const int* __restrict__ step,
    const float* __restrict__ Wo, const float* __restrict__ bo,
    const float* __restrict__ wsum, const float* __restrict__ sumexp,
    const float* __restrict__ tsum, float* __restrict__ d_out, int shifted)
{
    __shared__ float bnon[HD], bdeb[HD], bnon2[HD], bdeb2[HD];
    const int b = blockIdx.x;
    const int f = b >> 8;                       // 256 blocks per faction
    const int fn = (f + 1 < NF) ? f + 1 : f;    // spillover faction
    {
        const int jc = threadIdx.x & 127;
        const int useF = (threadIdx.x < 128) ? f : fn;
        float s = 0.f, fm_s = 0.f;
        #pragma unroll
        for (int rr = 0; rr < NREP; ++rr) {
            #pragma unroll
            for (int ff = 0; ff < NF; ++ff) s += fsum[(rr*NF+ff)*HD + jc];
            fm_s += fsum[(rr*NF+useF)*HD + jc];
        }
        const float go = s * (1.0f/NCELLS);
        const float fm = fm_s * (1.0f/FS);
        if (threadIdx.x < 128) { bnon[jc] = 0.15f*fm;  bdeb[jc] = 0.1275f*fm + 0.15f*go; }
        else                   { bnon2[jc] = 0.15f*fm; bdeb2[jc] = 0.1275f*fm + 0.15f*go; }
    }
    __syncthreads();
    const int sglob = (step[0] > 5) ? 1 : 0;

    if (shifted) {
        const int Fbase = b * 2048;             // float4 index space over scratch
        #pragma unroll
        for (int it = 0; it < 8; ++it) {
            const int F  = Fbase + threadIdx.x + it*256;
            const int g0 = 4*F + 3;             // dst element of comp0 (16B-aligned)
            float4 v = ((const float4*)src)[F];
            const int c0 = g0 >> 7, j0 = g0 & 127;
            const int d0 = sglob && ((c0 & (FS-1)) < DC);
            const float a0 = d0 ? 0.7225f : 0.85f;
            const float* br0 = d0 ? bdeb : bnon;
            float r0 = a0*v.x + br0[j0], r1, r2, r3;
            if (j0 != 127) {                    // all 4 comps in cell c0
                r1 = a0*v.y + br0[j0+1];
                r2 = a0*v.z + br0[j0+2];
                r3 = a0*v.w + br0[j0+3];
            } else {                            // comps 1-3 in cell c0+1
                const int c1 = c0 + 1;
                const int d1 = sglob && ((c1 & (FS-1)) < DC);
                const float a1 = d1 ? 0.7225f : 0.85f;
                const bool nf2 = (c1 >> 14) != f;
                const float* br1 = nf2 ? (d1 ? bdeb2 : bnon2) : (d1 ? bdeb : bnon);
                r1 = a1*v.y + br1[0];
                r2 = a1*v.z + br1[1];
                r3 = a1*v.w + br1[2];
            }
            if (g0 + 3 < NT) {
                float4 o = {r0, r1, r2, r3};
                *(float4*)(dst + g0) = o;
            } else {
                dst[g0] = r0;                   // final partial (g0 == NT-1)
            }
        }
        if (b == 0 && threadIdx.x < 3) {        // head elements g=0,1,2 (cell 0, f=0)
            const int g = threadIdx.x;
            const float a0 = sglob ? 0.7225f : 0.85f;
            const float* br0 = sglob ? bdeb : bnon;
            dst[g] = a0 * src[NT - 3 + g] + br0[g];
        }
    } else {                                    // fallback: unshifted scalar path
        const int cell0 = b * TBF;
        const bool debate = sglob && ((cell0 & (FS-1)) < DC);
        const float a = debate ? 0.7225f : 0.85f;
        const float* brow = debate ? bdeb : bnon;
        const float* srow = src + (size_t)cell0*HD;
        float* drow = dst + (size_t)cell0*HD;
        #pragma unroll
        for (int i = 0; i < (TBF*HD)/256; ++i) {
            const int idx = threadIdx.x + i*256;
            drow[idx] = a*srow[idx] + brow[idx & 127];
        }
    }

    if (b == 0 && threadIdx.x < OUTD) {         // fused final head
        const int i = threadIdx.x;
        float seT = 0.f;
        #pragma unroll
        for (int rr = 0; rr < NREP; ++rr) seT += sumexp[rr];
        const float inv = 1.0f / seT;
        const float* wr = Wo + (size_t)i*OUTD;
        float acc = bo[i];
        #pragma unroll 8
        for (int jj = 0; jj < OUTD; ++jj) {
            float wv = wsum[jj] + wsum[64+jj] + wsum[128+jj] + wsum[192+jj];
            acc += (wv*inv) * wr[jj];
        }
        d_out[i] = acc;
        if (i == 0) {
            float tT = 0.f;
            #pragma unroll
            for (int rr = 0; rr < NREP; ++rr) tT += tsum[rr];
            d_out[OUTD] = tT * (1.0f/NCELLS);
        }
    }
}

extern "C" void kernel_launch(void* const* d_in, const int* in_sizes, int n_in,
                              void* d_out, int out_size, void* d_ws, size_t ws_size,
                              hipStream_t stream)
{
    const float* x   = (const float*)d_in[0];
    const float* hid = (const float*)d_in[1];
    const float* W1a = (const float*)d_in[2];
    const float* b1a = (const float*)d_in[3];
    const float* W2a = (const float*)d_in[4];
    const float* b2a = (const float*)d_in[5];
    const float* W1g = (const float*)d_in[6];
    const float* b1g = (const float*)d_in[7];
    const float* W2g = (const float*)d_in[8];
    const float* b2g = (const float*)d_in[9];
    const float* Wih = (const float*)d_in[10];
    const float* Whh = (const float*)d_in[11];
    const float* bih = (const float*)d_in[12];
    const float* bhh = (const float*)d_in[13];
    const float* Wo  = (const float*)d_in[14];
    const float* bo  = (const float*)d_in[15];
    const int*  step = (const int*)d_in[16];

    float* out  = (float*)d_out;
    float* newh_out = out + (OUTD + 1);

    unsigned short* wsu = (unsigned short*)d_ws;
    float* wsf = (float*)(wsu + WS_U_TOTAL);
    float* fsum   = wsf + WF_FSUM;
    float* wsum   = wsf + WF_WSUM;
    float* sumexp = wsf + WF_SE;
    float* tsum   = wsf + WF_TS;

    const size_t need = (size_t)WS_NH_OFF + (size_t)NT*sizeof(float);
    const int shifted = (ws_size >= need) ? 1 : 0;
    float* nh_store = shifted ? (float*)((char*)d_ws + WS_NH_OFF) : newh_out;

    hipMemsetAsync(fsum, 0, (NREP*NF*HD + NREP*OUTD + 2*NREP)*sizeof(float), stream);

    convert_kernel<<<(123584 + 255)/256, 256, 0, stream>>>(
        x, W1a, b1a, W2a, b2a, W1g, b1g, W2g, b2g, Wih, Whh, wsu, wsf);

    fused_cell_kernel<<<NBLK, NTH, 0, stream>>>(
        hid, bih, bhh, wsu, wsf, nh_store, fsum, wsum, sumexp, tsum, shifted);

    faction_kernel<<<NCELLS/TBF, 256, 0, stream>>>(
        nh_store, newh_out, fsum, step, Wo, bo, wsum, sumexp, tsum, out, shifted);
}